// Round 4
// baseline (1546.314 us; speedup 1.0000x reference)
//
#include <hip/hip_runtime.h>

// GraphSAGE 2-layer encoder, fp32 — bucketed counting-sort + LDS-SpMM.
// R3 postmortem: fill_kernel had 16x write amplification (105MB HBM writes for
// a 6.4MB payload; random 4B scatter + 1.6M atomic-returns). R4: partition
// edges into 128-node buckets (packed u32 = src<<7 | dst_local), then one
// aggregate kernel per bucket accumulates transformed neighbor rows into a
// 35KB LDS accumulator with ds_add_f32 and applies the fused epilogue.
// No CSR, no sorted_src, no N-wide scans.

#define DIM 64
#define BNODES 128            // nodes per bucket (dst >> 7)
#define MAXBUCK 1024          // static LDS histogram bound (need nbuck <= 1023)
#define CHUNK 8192            // edges per partition/prehist block

__device__ inline void fma4(float4& acc, float s, const float4 w) {
    acc.x = fmaf(s, w.x, acc.x); acc.y = fmaf(s, w.y, acc.y);
    acc.z = fmaf(s, w.z, acc.z); acc.w = fmaf(s, w.w, acc.w);
}

// ---- pre-histogram: global bucket counts ----
__global__ __launch_bounds__(256) void prehist_kernel(const int* __restrict__ dst,
                                                      int* __restrict__ ghist,
                                                      int nE, int nbuck) {
    __shared__ int hist[MAXBUCK];
    const int t = threadIdx.x;
    for (int b = t; b < nbuck; b += 256) hist[b] = 0;
    __syncthreads();
    const int base = blockIdx.x * CHUNK;
    const int end = min(nE, base + CHUNK);
    for (int i = base + t; i < end; i += 256)
        atomicAdd(&hist[dst[i] >> 7], 1);
    __syncthreads();
    for (int b = t; b < nbuck; b += 256)
        if (hist[b]) atomicAdd(&ghist[b], hist[b]);
}

// ---- exclusive scan of bucket counts (single block), writes boff + gcur ----
__global__ __launch_bounds__(256) void scan_kernel(const int* __restrict__ ghist,
                                                   int* __restrict__ boff,
                                                   int* __restrict__ gcur, int nbuck) {
    __shared__ int sh[256];
    const int t = threadIdx.x;
    int v[4];
    int s = 0;
#pragma unroll
    for (int i = 0; i < 4; ++i) {
        int idx = t * 4 + i;
        v[i] = (idx < nbuck) ? ghist[idx] : 0;
        s += v[i];
    }
    sh[t] = s;
    __syncthreads();
    for (int d = 1; d < 256; d <<= 1) {
        int u = (t >= d) ? sh[t - d] : 0;
        __syncthreads();
        sh[t] += u;
        __syncthreads();
    }
    int off = sh[t] - s;   // exclusive base for this thread's 4 entries
#pragma unroll
    for (int i = 0; i < 4; ++i) {
        int idx = t * 4 + i;
        if (idx <= nbuck) boff[idx] = off;
        if (idx < nbuck) gcur[idx] = off;
        off += v[i];
    }
}

// ---- partition: scatter packed (src<<7 | dst&127) into bucket regions ----
__global__ __launch_bounds__(256) void partition_kernel(const int* __restrict__ src,
                                                        const int* __restrict__ dst,
                                                        int* __restrict__ gcur,
                                                        unsigned* __restrict__ P,
                                                        int nE, int nbuck) {
    __shared__ int hist[MAXBUCK];
    const int t = threadIdx.x;
    for (int b = t; b < nbuck; b += 256) hist[b] = 0;
    __syncthreads();
    const int base = blockIdx.x * CHUNK;
    const int end = min(nE, base + CHUNK);
    for (int i = base + t; i < end; i += 256)
        atomicAdd(&hist[dst[i] >> 7], 1);
    __syncthreads();
    // reserve a contiguous slice of each bucket region for this block
    for (int b = t; b < nbuck; b += 256) {
        int h = hist[b];
        hist[b] = h ? atomicAdd(&gcur[b], h) : 0;
    }
    __syncthreads();
    for (int i = base + t; i < end; i += 256) {
        int d = dst[i];
        int bk = d >> 7;
        int pos = atomicAdd(&hist[bk], 1);
        P[pos] = ((unsigned)src[i] << 7) | (unsigned)(d & 127);
    }
}

// ---- dual GEMM: A = H@Wl ; D = H@Wr + bias (one pass over H) ----
__global__ __launch_bounds__(256) void dual_gemm(const float* __restrict__ H,
                                                 const float* __restrict__ Wl,
                                                 const float* __restrict__ Wr,
                                                 const float* __restrict__ bias,
                                                 float* __restrict__ A,
                                                 float* __restrict__ Dbuf, int n) {
    __shared__ float wsl[4096];
    __shared__ float wsr[4096];
    __shared__ float hs[64 * 68];
    __shared__ float bs[64];
    const int t = threadIdx.x;
    for (int i = t * 4; i < 4096; i += 1024) {
        *(float4*)&wsl[i] = *(const float4*)&Wl[i];
        *(float4*)&wsr[i] = *(const float4*)&Wr[i];
    }
    if (t < 16) *(float4*)&bs[t * 4] = *(const float4*)&bias[t * 4];
    const int base = blockIdx.x * 64;
    for (int p = 0; p < 4; ++p) {
        int idx = t + p * 256;
        int r = idx >> 4, c4 = idx & 15;
        int row = base + r;
        if (row < n)
            *(float4*)&hs[r * 68 + c4 * 4] = *(const float4*)&H[(size_t)row * 64 + c4 * 4];
    }
    __syncthreads();
    const int dg = t & 15;
    const int r0 = t >> 4;
    float4 accl[4] = {{0,0,0,0},{0,0,0,0},{0,0,0,0},{0,0,0,0}};
    float4 accr[4] = {{0,0,0,0},{0,0,0,0},{0,0,0,0},{0,0,0,0}};
#pragma unroll 4
    for (int kq = 0; kq < 16; ++kq) {
        float4 wl[4], wr[4];
#pragma unroll
        for (int i = 0; i < 4; ++i) {
            wl[i] = *(const float4*)&wsl[(kq * 4 + i) * 64 + dg * 4];
            wr[i] = *(const float4*)&wsr[(kq * 4 + i) * 64 + dg * 4];
        }
#pragma unroll
        for (int p = 0; p < 4; ++p) {
            float4 hv = *(const float4*)&hs[(r0 + p * 16) * 68 + kq * 4];
            fma4(accl[p], hv.x, wl[0]); fma4(accl[p], hv.y, wl[1]);
            fma4(accl[p], hv.z, wl[2]); fma4(accl[p], hv.w, wl[3]);
            fma4(accr[p], hv.x, wr[0]); fma4(accr[p], hv.y, wr[1]);
            fma4(accr[p], hv.z, wr[2]); fma4(accr[p], hv.w, wr[3]);
        }
    }
    float4 b4 = *(const float4*)&bs[dg * 4];
#pragma unroll
    for (int p = 0; p < 4; ++p) {
        int row = base + r0 + p * 16;
        if (row < n) {
            *(float4*)&A[(size_t)row * 64 + dg * 4] = accl[p];
            float4 d;
            d.x = accr[p].x + b4.x; d.y = accr[p].y + b4.y;
            d.z = accr[p].z + b4.z; d.w = accr[p].w + b4.w;
            *(float4*)&Dbuf[(size_t)row * 64 + dg * 4] = d;
        }
    }
}

// ---- aggregate: per 128-node bucket, LDS-accumulate neighbor rows of Y,
//      then out = act(acc*inv_deg + D) ----
template <bool RELU>
__global__ __launch_bounds__(256) void aggregate_kernel(const float* __restrict__ Y,
                                                        const float* __restrict__ Dbuf,
                                                        const int* __restrict__ boff,
                                                        const unsigned* __restrict__ P,
                                                        float* __restrict__ out, int n) {
    __shared__ float acc[BNODES * 68];   // stride 68 to spread banks
    __shared__ int dcnt[BNODES];
    const int t = threadIdx.x;
    for (int i = t; i < BNODES * 68; i += 256) acc[i] = 0.f;
    if (t < BNODES) dcnt[t] = 0;
    __syncthreads();
    const int b = blockIdx.x;
    const int start = boff[b], end = boff[b + 1];
    const int g = t >> 4, dg = t & 15;
    for (int i = start + g; i < end; i += 16) {
        unsigned p = P[i];
        int s = (int)(p >> 7);
        int dl = (int)(p & 127);
        float4 v = *(const float4*)&Y[(size_t)s * 64 + dg * 4];
        float* ap = &acc[dl * 68 + dg * 4];
        atomicAdd(ap + 0, v.x);
        atomicAdd(ap + 1, v.y);
        atomicAdd(ap + 2, v.z);
        atomicAdd(ap + 3, v.w);
        if (dg == 0) atomicAdd(&dcnt[dl], 1);
    }
    __syncthreads();
    const int nodebase = b * BNODES;
#pragma unroll
    for (int pass = 0; pass < 8; ++pass) {
        int idx = pass * 256 + t;
        int nl = idx >> 4, d4 = idx & 15;
        int node = nodebase + nl;
        if (node < n) {
            float inv = 1.0f / fmaxf((float)dcnt[nl], 1.0f);
            float4 a = *(const float4*)&acc[nl * 68 + d4 * 4];
            float4 dd = *(const float4*)&Dbuf[(size_t)node * 64 + d4 * 4];
            float4 o;
            o.x = fmaf(a.x, inv, dd.x);
            o.y = fmaf(a.y, inv, dd.y);
            o.z = fmaf(a.z, inv, dd.z);
            o.w = fmaf(a.w, inv, dd.w);
            if (RELU) {
                o.x = fmaxf(o.x, 0.f); o.y = fmaxf(o.y, 0.f);
                o.z = fmaxf(o.z, 0.f); o.w = fmaxf(o.w, 0.f);
            }
            *(float4*)&out[(size_t)node * 64 + d4 * 4] = o;
        }
    }
}

extern "C" void kernel_launch(void* const* d_in, const int* in_sizes, int n_in,
                              void* d_out, int out_size, void* d_ws, size_t ws_size,
                              hipStream_t stream) {
    const float* x   = (const float*)d_in[0];
    const int*   ei  = (const int*)d_in[1];
    const float* w1l = (const float*)d_in[2];
    const float* b1l = (const float*)d_in[3];
    const float* w1r = (const float*)d_in[4];
    const float* w2l = (const float*)d_in[5];
    const float* b2l = (const float*)d_in[6];
    const float* w2r = (const float*)d_in[7];
    float* out = (float*)d_out;

    const int N = in_sizes[0] / DIM;   // 100000
    const int E = in_sizes[1] / 2;     // 1600000
    const int* src = ei;
    const int* dst = ei + E;
    const int nbuck = (N + BNODES - 1) / BNODES;   // 782

    // ws: ghist[nbuck] | boff[nbuck+1] | gcur[nbuck] | P[E] | A[N*64] | D[N*64]
    int* ghist = (int*)d_ws;
    int* boff = ghist + nbuck;
    int* gcur = boff + nbuck + 1;
    unsigned* P = (unsigned*)(gcur + nbuck);
    float* A = (float*)(P + E);
    float* D = A + (size_t)N * DIM;
    float* h1 = out;                    // layer-1 output reuses d_out

    const int pb = (E + CHUNK - 1) / CHUNK;        // 196
    const int gb = (N + 63) / 64;                  // 1563

    // ---- bucket build ----
    hipMemsetAsync(ghist, 0, nbuck * sizeof(int), stream);
    prehist_kernel<<<pb, 256, 0, stream>>>(dst, ghist, E, nbuck);
    scan_kernel<<<1, 256, 0, stream>>>(ghist, boff, gcur, nbuck);
    partition_kernel<<<pb, 256, 0, stream>>>(src, dst, gcur, P, E, nbuck);

    // ---- layer 1 ----
    dual_gemm<<<gb, 256, 0, stream>>>(x, w1l, w1r, b1l, A, D, N);
    aggregate_kernel<true><<<nbuck, 256, 0, stream>>>(A, D, boff, P, h1, N);

    // ---- layer 2 ----
    dual_gemm<<<gb, 256, 0, stream>>>(h1, w2l, w2r, b2l, A, D, N);
    aggregate_kernel<false><<<nbuck, 256, 0, stream>>>(A, D, boff, P, out, N);
}

// Round 5
// 368.676 us; speedup vs baseline: 4.1942x; 4.1942x over previous
//
#include <hip/hip_runtime.h>

// GraphSAGE 2-layer encoder, fp32 — two-level counting sort -> CSR -> gather.
// R4 postmortem: LDS-atomic aggregation was latency-bound (684us, 782 blocks,
// serial dependent chains). Reverted to R3's register-accumulate gather_combine
// (fast) and fixed R3's real problem (fill_kernel 16x write amplification) with
// a two-level sort: bucket partition (block-private contiguous slices, write
// amp ~1, measured fast in R4) + per-bucket LDS counting sort into final CSR.

#define DIM 64
#define BNODES 128            // nodes per bucket
#define MAXBUCK 1024          // LDS histogram bound (nbuck=782)
#define CHUNK 8192            // edges per partition/prehist block

__device__ inline void fma4(float4& acc, float s, const float4 w) {
    acc.x = fmaf(s, w.x, acc.x); acc.y = fmaf(s, w.y, acc.y);
    acc.z = fmaf(s, w.z, acc.z); acc.w = fmaf(s, w.w, acc.w);
}

// ---- pre-histogram: global bucket counts ----
__global__ __launch_bounds__(256) void prehist_kernel(const int* __restrict__ dst,
                                                      int* __restrict__ ghist,
                                                      int nE, int nbuck) {
    __shared__ int hist[MAXBUCK];
    const int t = threadIdx.x;
    for (int b = t; b < nbuck; b += 256) hist[b] = 0;
    __syncthreads();
    const int base = blockIdx.x * CHUNK;
    const int end = min(nE, base + CHUNK);
    for (int i = base + t; i < end; i += 256)
        atomicAdd(&hist[dst[i] >> 7], 1);
    __syncthreads();
    for (int b = t; b < nbuck; b += 256)
        if (hist[b]) atomicAdd(&ghist[b], hist[b]);
}

// ---- exclusive scan of bucket counts (single block) -> boff[nbuck+1], gcur ----
__global__ __launch_bounds__(256) void scan_kernel(const int* __restrict__ ghist,
                                                   int* __restrict__ boff,
                                                   int* __restrict__ gcur, int nbuck) {
    __shared__ int sh[256];
    const int t = threadIdx.x;
    int v[4];
    int s = 0;
#pragma unroll
    for (int i = 0; i < 4; ++i) {
        int idx = t * 4 + i;
        v[i] = (idx < nbuck) ? ghist[idx] : 0;
        s += v[i];
    }
    sh[t] = s;
    __syncthreads();
    for (int d = 1; d < 256; d <<= 1) {
        int u = (t >= d) ? sh[t - d] : 0;
        __syncthreads();
        sh[t] += u;
        __syncthreads();
    }
    int off = sh[t] - s;
#pragma unroll
    for (int i = 0; i < 4; ++i) {
        int idx = t * 4 + i;
        if (idx <= nbuck) boff[idx] = off;
        if (idx < nbuck) gcur[idx] = off;
        off += v[i];
    }
}

// ---- partition: scatter packed (src<<7 | dst&127) into bucket regions.
// Each block reserves contiguous per-bucket slices -> write amp ~1.
__global__ __launch_bounds__(256) void partition_kernel(const int* __restrict__ src,
                                                        const int* __restrict__ dst,
                                                        int* __restrict__ gcur,
                                                        unsigned* __restrict__ P,
                                                        int nE, int nbuck) {
    __shared__ int hist[MAXBUCK];
    const int t = threadIdx.x;
    for (int b = t; b < nbuck; b += 256) hist[b] = 0;
    __syncthreads();
    const int base = blockIdx.x * CHUNK;
    const int end = min(nE, base + CHUNK);
    for (int i = base + t; i < end; i += 256)
        atomicAdd(&hist[dst[i] >> 7], 1);
    __syncthreads();
    for (int b = t; b < nbuck; b += 256) {
        int h = hist[b];
        hist[b] = h ? atomicAdd(&gcur[b], h) : 0;
    }
    __syncthreads();
    for (int i = base + t; i < end; i += 256) {
        int d = dst[i];
        int bk = d >> 7;
        int pos = atomicAdd(&hist[bk], 1);
        P[pos] = ((unsigned)src[i] << 7) | (unsigned)(d & 127);
    }
}

// ---- local CSR: per bucket, counting-sort packed edges into final CSR.
// Writes confined to the bucket's own contiguous region (~8KB) -> write amp ~1.
// rowptr comes out globally contiguous (cnt[i] = rowptr[i+1]-rowptr[i]).
__global__ __launch_bounds__(256) void local_csr_kernel(const unsigned* __restrict__ P,
                                                        const int* __restrict__ boff,
                                                        int* __restrict__ rowptr,
                                                        int* __restrict__ sorted_src,
                                                        int n, int nbuck) {
    __shared__ int hist[BNODES];
    __shared__ int cur[BNODES];
    const int t = threadIdx.x;
    const int b = blockIdx.x;
    if (t < BNODES) hist[t] = 0;
    __syncthreads();
    const int start = boff[b], end = boff[b + 1];
    for (int i = start + t; i < end; i += 256)
        atomicAdd(&hist[P[i] & 127], 1);
    __syncthreads();
    if (t < BNODES) cur[t] = hist[t];
    __syncthreads();
    for (int d = 1; d < BNODES; d <<= 1) {
        int v = (t < BNODES && t >= d) ? cur[t - d] : 0;
        __syncthreads();
        if (t < BNODES) cur[t] += v;
        __syncthreads();
    }
    if (t < BNODES) {
        int excl = cur[t] - hist[t];
        int node = b * BNODES + t;
        if (node < n) rowptr[node] = start + excl;
        cur[t] = excl;
    }
    if (b == nbuck - 1 && t == 0) rowptr[n] = end;
    __syncthreads();
    for (int i = start + t; i < end; i += 256) {
        unsigned p = P[i];
        int dl = (int)(p & 127);
        int pos = atomicAdd(&cur[dl], 1);
        sorted_src[start + pos] = (int)(p >> 7);
    }
}

// ---- dual GEMM: A = H@Wl ; D = H@Wr + bias (one pass over H) ----
__global__ __launch_bounds__(256) void dual_gemm(const float* __restrict__ H,
                                                 const float* __restrict__ Wl,
                                                 const float* __restrict__ Wr,
                                                 const float* __restrict__ bias,
                                                 float* __restrict__ A,
                                                 float* __restrict__ Dbuf, int n) {
    __shared__ float wsl[4096];
    __shared__ float wsr[4096];
    __shared__ float hs[64 * 68];
    __shared__ float bs[64];
    const int t = threadIdx.x;
    for (int i = t * 4; i < 4096; i += 1024) {
        *(float4*)&wsl[i] = *(const float4*)&Wl[i];
        *(float4*)&wsr[i] = *(const float4*)&Wr[i];
    }
    if (t < 16) *(float4*)&bs[t * 4] = *(const float4*)&bias[t * 4];
    const int base = blockIdx.x * 64;
    for (int p = 0; p < 4; ++p) {
        int idx = t + p * 256;
        int r = idx >> 4, c4 = idx & 15;
        int row = base + r;
        if (row < n)
            *(float4*)&hs[r * 68 + c4 * 4] = *(const float4*)&H[(size_t)row * 64 + c4 * 4];
    }
    __syncthreads();
    const int dg = t & 15;
    const int r0 = t >> 4;
    float4 accl[4] = {{0,0,0,0},{0,0,0,0},{0,0,0,0},{0,0,0,0}};
    float4 accr[4] = {{0,0,0,0},{0,0,0,0},{0,0,0,0},{0,0,0,0}};
#pragma unroll 4
    for (int kq = 0; kq < 16; ++kq) {
        float4 wl[4], wr[4];
#pragma unroll
        for (int i = 0; i < 4; ++i) {
            wl[i] = *(const float4*)&wsl[(kq * 4 + i) * 64 + dg * 4];
            wr[i] = *(const float4*)&wsr[(kq * 4 + i) * 64 + dg * 4];
        }
#pragma unroll
        for (int p = 0; p < 4; ++p) {
            float4 hv = *(const float4*)&hs[(r0 + p * 16) * 68 + kq * 4];
            fma4(accl[p], hv.x, wl[0]); fma4(accl[p], hv.y, wl[1]);
            fma4(accl[p], hv.z, wl[2]); fma4(accl[p], hv.w, wl[3]);
            fma4(accr[p], hv.x, wr[0]); fma4(accr[p], hv.y, wr[1]);
            fma4(accr[p], hv.z, wr[2]); fma4(accr[p], hv.w, wr[3]);
        }
    }
    float4 b4 = *(const float4*)&bs[dg * 4];
#pragma unroll
    for (int p = 0; p < 4; ++p) {
        int row = base + r0 + p * 16;
        if (row < n) {
            *(float4*)&A[(size_t)row * 64 + dg * 4] = accl[p];
            float4 d;
            d.x = accr[p].x + b4.x; d.y = accr[p].y + b4.y;
            d.z = accr[p].z + b4.z; d.w = accr[p].w + b4.w;
            *(float4*)&Dbuf[(size_t)row * 64 + dg * 4] = d;
        }
    }
}

// ---- gather + combine: out = act( mean_{s in N(row)} Y[s] + D[row] ) ----
template <bool RELU>
__global__ __launch_bounds__(256) void gather_combine(const float* __restrict__ Y,
                                                      const float* __restrict__ Dbuf,
                                                      const int* __restrict__ rowptr,
                                                      const int* __restrict__ sorted_src,
                                                      float* __restrict__ out, int n) {
    const int t = threadIdx.x;
    const int row = blockIdx.x * 16 + (t >> 4);
    if (row >= n) return;
    const int dg = t & 15;
    const int start = rowptr[row];
    const int c = rowptr[row + 1] - start;
    const int* sp = sorted_src + start;
    float4 sum = {0.f, 0.f, 0.f, 0.f};
    int j = 0;
    for (; j + 4 <= c; j += 4) {
        int s0 = sp[j + 0], s1 = sp[j + 1], s2 = sp[j + 2], s3 = sp[j + 3];
        float4 v0 = *(const float4*)&Y[(size_t)s0 * 64 + dg * 4];
        float4 v1 = *(const float4*)&Y[(size_t)s1 * 64 + dg * 4];
        float4 v2 = *(const float4*)&Y[(size_t)s2 * 64 + dg * 4];
        float4 v3 = *(const float4*)&Y[(size_t)s3 * 64 + dg * 4];
        sum.x += (v0.x + v1.x) + (v2.x + v3.x);
        sum.y += (v0.y + v1.y) + (v2.y + v3.y);
        sum.z += (v0.z + v1.z) + (v2.z + v3.z);
        sum.w += (v0.w + v1.w) + (v2.w + v3.w);
    }
    for (; j < c; ++j) {
        int s = sp[j];
        float4 v = *(const float4*)&Y[(size_t)s * 64 + dg * 4];
        sum.x += v.x; sum.y += v.y; sum.z += v.z; sum.w += v.w;
    }
    const float inv = 1.0f / fmaxf((float)c, 1.0f);
    float4 d4 = *(const float4*)&Dbuf[(size_t)row * 64 + dg * 4];
    float4 o;
    o.x = fmaf(sum.x, inv, d4.x);
    o.y = fmaf(sum.y, inv, d4.y);
    o.z = fmaf(sum.z, inv, d4.z);
    o.w = fmaf(sum.w, inv, d4.w);
    if (RELU) {
        o.x = fmaxf(o.x, 0.f); o.y = fmaxf(o.y, 0.f);
        o.z = fmaxf(o.z, 0.f); o.w = fmaxf(o.w, 0.f);
    }
    *(float4*)&out[(size_t)row * 64 + dg * 4] = o;
}

extern "C" void kernel_launch(void* const* d_in, const int* in_sizes, int n_in,
                              void* d_out, int out_size, void* d_ws, size_t ws_size,
                              hipStream_t stream) {
    const float* x   = (const float*)d_in[0];
    const int*   ei  = (const int*)d_in[1];
    const float* w1l = (const float*)d_in[2];
    const float* b1l = (const float*)d_in[3];
    const float* w1r = (const float*)d_in[4];
    const float* w2l = (const float*)d_in[5];
    const float* b2l = (const float*)d_in[6];
    const float* w2r = (const float*)d_in[7];
    float* out = (float*)d_out;

    const int N = in_sizes[0] / DIM;   // 100000
    const int E = in_sizes[1] / 2;     // 1600000
    const int* src = ei;
    const int* dst = ei + E;
    const int nbuck = (N + BNODES - 1) / BNODES;   // 782

    // ws: ghist[nbuck] | boff[nbuck+1] | gcur[nbuck] | rowptr[N+1] |
    //     P[E] | sorted_src[E] | A[N*64] | D[N*64]
    int* ghist = (int*)d_ws;
    int* boff = ghist + nbuck;
    int* gcur = boff + nbuck + 1;
    int* rowptr = gcur + nbuck;
    unsigned* P = (unsigned*)(rowptr + N + 1);
    int* sorted_src = (int*)(P + E);
    float* A = (float*)(sorted_src + E);
    float* D = A + (size_t)N * DIM;
    float* h1 = out;                    // layer-1 output reuses d_out

    const int pb = (E + CHUNK - 1) / CHUNK;        // 196
    const int gb = (N + 63) / 64;                  // 1563
    const int cb = (N + 15) / 16;                  // 6250

    // ---- two-level sort -> CSR ----
    hipMemsetAsync(ghist, 0, nbuck * sizeof(int), stream);
    prehist_kernel<<<pb, 256, 0, stream>>>(dst, ghist, E, nbuck);
    scan_kernel<<<1, 256, 0, stream>>>(ghist, boff, gcur, nbuck);
    partition_kernel<<<pb, 256, 0, stream>>>(src, dst, gcur, P, E, nbuck);
    local_csr_kernel<<<nbuck, 256, 0, stream>>>(P, boff, rowptr, sorted_src, N, nbuck);

    // ---- layer 1 ----
    dual_gemm<<<gb, 256, 0, stream>>>(x, w1l, w1r, b1l, A, D, N);
    gather_combine<true><<<cb, 256, 0, stream>>>(A, D, rowptr, sorted_src, h1, N);

    // ---- layer 2 ----
    dual_gemm<<<gb, 256, 0, stream>>>(h1, w2l, w2r, b2l, A, D, N);
    gather_combine<false><<<cb, 256, 0, stream>>>(A, D, rowptr, sorted_src, out, N);
}

// Round 6
// 310.222 us; speedup vs baseline: 4.9845x; 1.1884x over previous
//
#include <hip/hip_runtime.h>
#include <hip/hip_fp16.h>

// GraphSAGE 2-layer encoder — two-level counting sort -> CSR -> fp16 gather.
// R5 postmortem: gather_combine is traffic-bound (274MB fetch/dispatch = full
// fp32 Y row traffic, 3.6TB/s, VALU 8.6%). R6: store transformed table Y in
// fp16 (halves per-edge bytes AND doubles L2 coverage of the hot set); gather
// uses 8 lanes/row x 16B half8 loads (coalescing sweet spot), 4-way unroll.
// Self-path D and all epilogue math stay fp32 (threshold 3.3e-2, fp16 err ~5e-4).

#define DIM 64
#define BNODES 128            // nodes per bucket
#define MAXBUCK 1024          // LDS histogram bound (nbuck=782)
#define CHUNK 8192            // edges per partition/prehist block

__device__ inline void fma4(float4& acc, float s, const float4 w) {
    acc.x = fmaf(s, w.x, acc.x); acc.y = fmaf(s, w.y, acc.y);
    acc.z = fmaf(s, w.z, acc.z); acc.w = fmaf(s, w.w, acc.w);
}

// accumulate 8 halves (loaded as float4 bit-pattern) into acc[8]
__device__ inline void addh8(float* acc, float4 raw) {
    const __half2* hp = (const __half2*)&raw;
#pragma unroll
    for (int k = 0; k < 4; ++k) {
        float2 f = __half22float2(hp[k]);
        acc[2 * k]     += f.x;
        acc[2 * k + 1] += f.y;
    }
}

// ---- pre-histogram: global bucket counts ----
__global__ __launch_bounds__(256) void prehist_kernel(const int* __restrict__ dst,
                                                      int* __restrict__ ghist,
                                                      int nE, int nbuck) {
    __shared__ int hist[MAXBUCK];
    const int t = threadIdx.x;
    for (int b = t; b < nbuck; b += 256) hist[b] = 0;
    __syncthreads();
    const int base = blockIdx.x * CHUNK;
    const int end = min(nE, base + CHUNK);
    for (int i = base + t; i < end; i += 256)
        atomicAdd(&hist[dst[i] >> 7], 1);
    __syncthreads();
    for (int b = t; b < nbuck; b += 256)
        if (hist[b]) atomicAdd(&ghist[b], hist[b]);
}

// ---- exclusive scan of bucket counts (single block) -> boff[nbuck+1], gcur ----
__global__ __launch_bounds__(256) void scan_kernel(const int* __restrict__ ghist,
                                                   int* __restrict__ boff,
                                                   int* __restrict__ gcur, int nbuck) {
    __shared__ int sh[256];
    const int t = threadIdx.x;
    int v[4];
    int s = 0;
#pragma unroll
    for (int i = 0; i < 4; ++i) {
        int idx = t * 4 + i;
        v[i] = (idx < nbuck) ? ghist[idx] : 0;
        s += v[i];
    }
    sh[t] = s;
    __syncthreads();
    for (int d = 1; d < 256; d <<= 1) {
        int u = (t >= d) ? sh[t - d] : 0;
        __syncthreads();
        sh[t] += u;
        __syncthreads();
    }
    int off = sh[t] - s;
#pragma unroll
    for (int i = 0; i < 4; ++i) {
        int idx = t * 4 + i;
        if (idx <= nbuck) boff[idx] = off;
        if (idx < nbuck) gcur[idx] = off;
        off += v[i];
    }
}

// ---- partition: scatter packed (src<<7 | dst&127) into bucket regions ----
__global__ __launch_bounds__(256) void partition_kernel(const int* __restrict__ src,
                                                        const int* __restrict__ dst,
                                                        int* __restrict__ gcur,
                                                        unsigned* __restrict__ P,
                                                        int nE, int nbuck) {
    __shared__ int hist[MAXBUCK];
    const int t = threadIdx.x;
    for (int b = t; b < nbuck; b += 256) hist[b] = 0;
    __syncthreads();
    const int base = blockIdx.x * CHUNK;
    const int end = min(nE, base + CHUNK);
    for (int i = base + t; i < end; i += 256)
        atomicAdd(&hist[dst[i] >> 7], 1);
    __syncthreads();
    for (int b = t; b < nbuck; b += 256) {
        int h = hist[b];
        hist[b] = h ? atomicAdd(&gcur[b], h) : 0;
    }
    __syncthreads();
    for (int i = base + t; i < end; i += 256) {
        int d = dst[i];
        int bk = d >> 7;
        int pos = atomicAdd(&hist[bk], 1);
        P[pos] = ((unsigned)src[i] << 7) | (unsigned)(d & 127);
    }
}

// ---- local CSR: per bucket, counting-sort packed edges into final CSR ----
__global__ __launch_bounds__(256) void local_csr_kernel(const unsigned* __restrict__ P,
                                                        const int* __restrict__ boff,
                                                        int* __restrict__ rowptr,
                                                        int* __restrict__ sorted_src,
                                                        int n, int nbuck) {
    __shared__ int hist[BNODES];
    __shared__ int cur[BNODES];
    const int t = threadIdx.x;
    const int b = blockIdx.x;
    if (t < BNODES) hist[t] = 0;
    __syncthreads();
    const int start = boff[b], end = boff[b + 1];
    for (int i = start + t; i < end; i += 256)
        atomicAdd(&hist[P[i] & 127], 1);
    __syncthreads();
    if (t < BNODES) cur[t] = hist[t];
    __syncthreads();
    for (int d = 1; d < BNODES; d <<= 1) {
        int v = (t < BNODES && t >= d) ? cur[t - d] : 0;
        __syncthreads();
        if (t < BNODES) cur[t] += v;
        __syncthreads();
    }
    if (t < BNODES) {
        int excl = cur[t] - hist[t];
        int node = b * BNODES + t;
        if (node < n) rowptr[node] = start + excl;
        cur[t] = excl;
    }
    if (b == nbuck - 1 && t == 0) rowptr[n] = end;
    __syncthreads();
    for (int i = start + t; i < end; i += 256) {
        unsigned p = P[i];
        int dl = (int)(p & 127);
        int pos = atomicAdd(&cur[dl], 1);
        sorted_src[start + pos] = (int)(p >> 7);
    }
}

// ---- dual GEMM: A(fp16) = H@Wl ; D(fp32) = H@Wr + bias (one pass over H) ----
__global__ __launch_bounds__(256) void dual_gemm(const float* __restrict__ H,
                                                 const float* __restrict__ Wl,
                                                 const float* __restrict__ Wr,
                                                 const float* __restrict__ bias,
                                                 __half* __restrict__ A,
                                                 float* __restrict__ Dbuf, int n) {
    __shared__ float wsl[4096];
    __shared__ float wsr[4096];
    __shared__ float hs[64 * 68];
    __shared__ float bs[64];
    const int t = threadIdx.x;
    for (int i = t * 4; i < 4096; i += 1024) {
        *(float4*)&wsl[i] = *(const float4*)&Wl[i];
        *(float4*)&wsr[i] = *(const float4*)&Wr[i];
    }
    if (t < 16) *(float4*)&bs[t * 4] = *(const float4*)&bias[t * 4];
    const int base = blockIdx.x * 64;
    for (int p = 0; p < 4; ++p) {
        int idx = t + p * 256;
        int r = idx >> 4, c4 = idx & 15;
        int row = base + r;
        if (row < n)
            *(float4*)&hs[r * 68 + c4 * 4] = *(const float4*)&H[(size_t)row * 64 + c4 * 4];
    }
    __syncthreads();
    const int dg = t & 15;
    const int r0 = t >> 4;
    float4 accl[4] = {{0,0,0,0},{0,0,0,0},{0,0,0,0},{0,0,0,0}};
    float4 accr[4] = {{0,0,0,0},{0,0,0,0},{0,0,0,0},{0,0,0,0}};
#pragma unroll 4
    for (int kq = 0; kq < 16; ++kq) {
        float4 wl[4], wr[4];
#pragma unroll
        for (int i = 0; i < 4; ++i) {
            wl[i] = *(const float4*)&wsl[(kq * 4 + i) * 64 + dg * 4];
            wr[i] = *(const float4*)&wsr[(kq * 4 + i) * 64 + dg * 4];
        }
#pragma unroll
        for (int p = 0; p < 4; ++p) {
            float4 hv = *(const float4*)&hs[(r0 + p * 16) * 68 + kq * 4];
            fma4(accl[p], hv.x, wl[0]); fma4(accl[p], hv.y, wl[1]);
            fma4(accl[p], hv.z, wl[2]); fma4(accl[p], hv.w, wl[3]);
            fma4(accr[p], hv.x, wr[0]); fma4(accr[p], hv.y, wr[1]);
            fma4(accr[p], hv.z, wr[2]); fma4(accr[p], hv.w, wr[3]);
        }
    }
    float4 b4 = *(const float4*)&bs[dg * 4];
#pragma unroll
    for (int p = 0; p < 4; ++p) {
        int row = base + r0 + p * 16;
        if (row < n) {
            union { __half2 h[2]; float2 f; } u;
            u.h[0] = __floats2half2_rn(accl[p].x, accl[p].y);
            u.h[1] = __floats2half2_rn(accl[p].z, accl[p].w);
            *(float2*)&A[(size_t)row * 64 + dg * 4] = u.f;
            float4 d;
            d.x = accr[p].x + b4.x; d.y = accr[p].y + b4.y;
            d.z = accr[p].z + b4.z; d.w = accr[p].w + b4.w;
            *(float4*)&Dbuf[(size_t)row * 64 + dg * 4] = d;
        }
    }
}

// ---- gather + combine: out = act( mean_{s in N(row)} Y[s] + D[row] ) ----
// 8 lanes/row, each lane owns 8 dims (one 16B half8 load per edge), 32 rows/blk.
template <bool RELU>
__global__ __launch_bounds__(256) void gather_combine(const __half* __restrict__ Y,
                                                      const float* __restrict__ Dbuf,
                                                      const int* __restrict__ rowptr,
                                                      const int* __restrict__ sorted_src,
                                                      float* __restrict__ out, int n) {
    const int t = threadIdx.x;
    const int row = blockIdx.x * 32 + (t >> 3);
    if (row >= n) return;
    const int dg = t & 7;
    const int start = rowptr[row];
    const int c = rowptr[row + 1] - start;
    const int* sp = sorted_src + start;
    float acc[8] = {0.f, 0.f, 0.f, 0.f, 0.f, 0.f, 0.f, 0.f};
    const size_t doff = (size_t)dg * 8;
    int j = 0;
    for (; j + 4 <= c; j += 4) {
        int e0 = sp[j + 0], e1 = sp[j + 1], e2 = sp[j + 2], e3 = sp[j + 3];
        float4 r0 = *(const float4*)&Y[(size_t)e0 * 64 + doff];
        float4 r1 = *(const float4*)&Y[(size_t)e1 * 64 + doff];
        float4 r2 = *(const float4*)&Y[(size_t)e2 * 64 + doff];
        float4 r3 = *(const float4*)&Y[(size_t)e3 * 64 + doff];
        addh8(acc, r0); addh8(acc, r1); addh8(acc, r2); addh8(acc, r3);
    }
    for (; j < c; ++j) {
        int s = sp[j];
        float4 r = *(const float4*)&Y[(size_t)s * 64 + doff];
        addh8(acc, r);
    }
    const float inv = 1.0f / fmaxf((float)c, 1.0f);
    float4 d0 = *(const float4*)&Dbuf[(size_t)row * 64 + doff];
    float4 d1 = *(const float4*)&Dbuf[(size_t)row * 64 + doff + 4];
    float4 o0, o1;
    o0.x = fmaf(acc[0], inv, d0.x); o0.y = fmaf(acc[1], inv, d0.y);
    o0.z = fmaf(acc[2], inv, d0.z); o0.w = fmaf(acc[3], inv, d0.w);
    o1.x = fmaf(acc[4], inv, d1.x); o1.y = fmaf(acc[5], inv, d1.y);
    o1.z = fmaf(acc[6], inv, d1.z); o1.w = fmaf(acc[7], inv, d1.w);
    if (RELU) {
        o0.x = fmaxf(o0.x, 0.f); o0.y = fmaxf(o0.y, 0.f);
        o0.z = fmaxf(o0.z, 0.f); o0.w = fmaxf(o0.w, 0.f);
        o1.x = fmaxf(o1.x, 0.f); o1.y = fmaxf(o1.y, 0.f);
        o1.z = fmaxf(o1.z, 0.f); o1.w = fmaxf(o1.w, 0.f);
    }
    *(float4*)&out[(size_t)row * 64 + doff] = o0;
    *(float4*)&out[(size_t)row * 64 + doff + 4] = o1;
}

extern "C" void kernel_launch(void* const* d_in, const int* in_sizes, int n_in,
                              void* d_out, int out_size, void* d_ws, size_t ws_size,
                              hipStream_t stream) {
    const float* x   = (const float*)d_in[0];
    const int*   ei  = (const int*)d_in[1];
    const float* w1l = (const float*)d_in[2];
    const float* b1l = (const float*)d_in[3];
    const float* w1r = (const float*)d_in[4];
    const float* w2l = (const float*)d_in[5];
    const float* b2l = (const float*)d_in[6];
    const float* w2r = (const float*)d_in[7];
    float* out = (float*)d_out;

    const int N = in_sizes[0] / DIM;   // 100000
    const int E = in_sizes[1] / 2;     // 1600000
    const int* src = ei;
    const int* dst = ei + E;
    const int nbuck = (N + BNODES - 1) / BNODES;   // 782

    // ws: ghist[nbuck] | boff[nbuck+1] | gcur[nbuck] | rowptr[N+1] |
    //     P[E] | sorted_src[E] | A_fp16[N*64] | D[N*64]
    int* ghist = (int*)d_ws;
    int* boff = ghist + nbuck;
    int* gcur = boff + nbuck + 1;
    int* rowptr = gcur + nbuck;
    unsigned* P = (unsigned*)(rowptr + N + 1);
    int* sorted_src = (int*)(P + E);
    __half* A = (__half*)(sorted_src + E);
    float* D = (float*)(A + (size_t)N * DIM);
    float* h1 = out;                    // layer-1 output reuses d_out

    const int pb = (E + CHUNK - 1) / CHUNK;        // 196
    const int gb = (N + 63) / 64;                  // 1563
    const int cb = (N + 31) / 32;                  // 3125

    // ---- two-level sort -> CSR ----
    hipMemsetAsync(ghist, 0, nbuck * sizeof(int), stream);
    prehist_kernel<<<pb, 256, 0, stream>>>(dst, ghist, E, nbuck);
    scan_kernel<<<1, 256, 0, stream>>>(ghist, boff, gcur, nbuck);
    partition_kernel<<<pb, 256, 0, stream>>>(src, dst, gcur, P, E, nbuck);
    local_csr_kernel<<<nbuck, 256, 0, stream>>>(P, boff, rowptr, sorted_src, N, nbuck);

    // ---- layer 1 ----
    dual_gemm<<<gb, 256, 0, stream>>>(x, w1l, w1r, b1l, A, D, N);
    gather_combine<true><<<cb, 256, 0, stream>>>(A, D, rowptr, sorted_src, h1, N);

    // ---- layer 2 ----
    dual_gemm<<<gb, 256, 0, stream>>>(h1, w2l, w2r, b2l, A, D, N);
    gather_combine<false><<<cb, 256, 0, stream>>>(A, D, rowptr, sorted_src, out, N);
}